// Round 1
// baseline (147.557 us; speedup 1.0000x reference)
//
#include <hip/hip_runtime.h>

// Problem constants (fixed by the reference's setup_inputs).
#define HREF   512
#define WREF   512
#define NBUCK  6
#define NLOOP  4
#define NDET   4096
#define NSAMP  128
#define BATCH  4
#define PLANE  (HREF * WREF)            // 262144 = 2^18
#define NCHAN  (2 * NBUCK)              // 12
#define RECSZ  16                       // floats per pixel record stride (64 B)

// ---------------------------------------------------------------------------
// Pre-pass: refinement[B][12][H][W] -> ws[B][H][W][16] pixel records laid out
// as [c0..c11, c0, c1, pad, pad].  The wrap-duplicate (c0,c1) at floats 12,13
// makes the 4 channels needed by any bucket pair (2bi..2bi+3 mod 12) a single
// CONTIGUOUS float4 at float offset 2*bi (max offset 10 -> floats 10..13,
// still inside the 64 B record).  Writes 56 B/record (pad not written).
// ---------------------------------------------------------------------------
__global__ __launch_bounds__(256) void CPN_transpose_kernel(
    const float* __restrict__ ref, float* __restrict__ ws)
{
    const int t = blockIdx.x * blockDim.x + threadIdx.x;   // [0, BATCH*PLANE)
    const int b = t >> 18;                                 // PLANE == 2^18
    const int p = t & (PLANE - 1);

    const float* src = ref + (size_t)b * NCHAN * PLANE + p;
    float* dst = ws + ((size_t)t << 4);

    float v[NCHAN + 2];
    #pragma unroll
    for (int c = 0; c < NCHAN; ++c) v[c] = src[(size_t)c << 18];
    v[12] = v[0];                                          // wrap duplicate
    v[13] = v[1];

    *(float4*)(dst + 0)  = make_float4(v[0], v[1], v[2],  v[3]);
    *(float4*)(dst + 4)  = make_float4(v[4], v[5], v[6],  v[7]);
    *(float4*)(dst + 8)  = make_float4(v[8], v[9], v[10], v[11]);
    *(float2*)(dst + 12) = make_float2(v[12], v[13]);
}

// ---------------------------------------------------------------------------
// Gather loop: ONE float4 load per loop iteration (was two float2).
// q = (c[2bi], c[2bi+1], c[2bj], c[2bj+1]) thanks to the wrap layout.
// ---------------------------------------------------------------------------
__global__ __launch_bounds__(256) void CPN_4492535791617_kernel(
    const float* __restrict__ det_in,
    const float* __restrict__ ws,
    const float* __restrict__ sampling,
    const int*   __restrict__ bsel,
    float*       __restrict__ out)
{
    const int tid = blockIdx.x * blockDim.x + threadIdx.x;   // [0, NDET*NSAMP)
    const int s = tid & (NSAMP - 1);
    const int d = tid >> 7;                                  // NSAMP == 128

    float2 det = ((const float2*)det_in)[tid];
    const int bb = bsel[d];

    // off=-1 always has weight 0 (d = frac+1 >= 1): only off=0 and off=+1 remain.
    const float base = sampling[s] * (float)NBUCK;
    const float bf   = floorf(base);
    const float frac = base - bf;
    const float w0   = 1.0f - frac;
    const float w1   = frac;
    int bi = (int)bf;
    if (bi >= NBUCK) bi -= NBUCK;
    if (bi < 0)      bi  = 0;

    // batch slab of records, channel offset folded into the base pointer
    const float* slab_bi = ws + ((size_t)bb << 22) + 2 * bi; // PLANE*16 floats/batch

    #pragma unroll
    for (int l = 0; l < NLOOP; ++l) {
        // jnp.round == round-half-to-even == rintf (RNE default).
        float x = rintf(det.x);
        float y = rintf(det.y);
        x = fminf(fmaxf(x, 0.0f), (float)(WREF - 1));
        y = fminf(fmaxf(y, 0.0f), (float)(HREF - 1));
        const int p = (int)y * WREF + (int)x;

        // 8 B aligned dwordx4, never crosses the 64 B record boundary.
        const float4 q = *(const float4*)(slab_bi + ((size_t)p << 4));

        det.x = x + (w0 * q.x + w1 * q.z);
        det.y = y + (w0 * q.y + w1 * q.w);
    }

    ((float2*)out)[tid] = det;
}

// ---------------------------------------------------------------------------
// Fallback (original plane-layout kernel) if ws is too small.
// ---------------------------------------------------------------------------
__global__ __launch_bounds__(256) void CPN_fallback_kernel(
    const float* __restrict__ det_in,
    const float* __restrict__ refinement,
    const float* __restrict__ sampling,
    const int*   __restrict__ bsel,
    float*       __restrict__ out)
{
    const int tid = blockIdx.x * blockDim.x + threadIdx.x;
    const int s = tid & (NSAMP - 1);
    const int d = tid >> 7;

    float2 det = ((const float2*)det_in)[tid];
    const int bb = bsel[d];

    const float base = sampling[s] * (float)NBUCK;
    const float bf   = floorf(base);
    const float frac = base - bf;
    const float w0   = 1.0f - frac;
    const float w1   = frac;
    int bi = (int)bf;
    if (bi >= NBUCK) bi -= NBUCK;
    if (bi < 0)      bi  = 0;
    int bj = bi + 1; if (bj >= NBUCK) bj -= NBUCK;

    const size_t plane = (size_t)PLANE;
    const float* slab = refinement + (size_t)bb * NCHAN * plane;
    const float* c0 = slab + (size_t)(2 * bi)     * plane;
    const float* c1 = slab + (size_t)(2 * bi + 1) * plane;
    const float* c2 = slab + (size_t)(2 * bj)     * plane;
    const float* c3 = slab + (size_t)(2 * bj + 1) * plane;

    #pragma unroll
    for (int l = 0; l < NLOOP; ++l) {
        float x = rintf(det.x);
        float y = rintf(det.y);
        x = fminf(fmaxf(x, 0.0f), (float)(WREF - 1));
        y = fminf(fmaxf(y, 0.0f), (float)(HREF - 1));
        const int p = (int)y * WREF + (int)x;
        det.x = x + (w0 * c0[p] + w1 * c2[p]);
        det.y = y + (w0 * c1[p] + w1 * c3[p]);
    }

    ((float2*)out)[tid] = det;
}

extern "C" void kernel_launch(void* const* d_in, const int* in_sizes, int n_in,
                              void* d_out, int out_size, void* d_ws, size_t ws_size,
                              hipStream_t stream) {
    const float* det_indices = (const float*)d_in[0];
    const float* refinement  = (const float*)d_in[1];
    const float* sampling    = (const float*)d_in[2];
    const int*   b           = (const int*)  d_in[3];
    float* out = (float*)d_out;

    const size_t need = (size_t)BATCH * PLANE * RECSZ * sizeof(float);  // 64 MB

    const int total = NDET * NSAMP;          // 524288 threads
    const int block = 256;
    const int grid  = total / block;         // 2048 blocks

    if (ws_size >= need) {
        float* ws = (float*)d_ws;
        const int tp_total = BATCH * PLANE;  // 1048576
        CPN_transpose_kernel<<<tp_total / block, block, 0, stream>>>(refinement, ws);
        CPN_4492535791617_kernel<<<grid, block, 0, stream>>>(
            det_indices, ws, sampling, b, out);
    } else {
        CPN_fallback_kernel<<<grid, block, 0, stream>>>(
            det_indices, refinement, sampling, b, out);
    }
}